// Round 1
// 285.062 us; speedup vs baseline: 1.0075x; 1.0075x over previous
//
#include <hip/hip_runtime.h>
#include <stdint.h>

// PointPillars constants (KITTI config)
#define GRID_X 432
#define GRID_Y 496
#define NB 4
#define NPTS 32
#define NC 64
#define NSLOTS 64
#define CELLS (GRID_Y * GRID_X)   // 214272 per batch (y-major, x fastest)
#define QUADS (CELLS / 4)         // 53568

constexpr float VXc = 0.16f, VYc = 0.16f;
constexpr float X_OFFSET = 0.08f, Y_OFFSET = -39.60f, Z_CONST = -1.0f;
constexpr float BN_EPS = 1e-3f;

// Kernel A: per-pillar sigma-space feature max per channel + BN stat partials + inverse map.
// sigma_c = sign(gamma[c]) is folded into the per-channel affine weights, so the
// selected extreme is ALWAYS a max (v' = sigma*v).  Downstream BN runs entirely in
// sigma-space: mu' = sigma*mu, var' = var, scale' = |gamma|*rsqrt(var+eps) >= 0,
// shift = beta - mu'*scale', y = scale'*v' + shift  ==  gamma*rsqrt*(v-mu)+beta.
__global__ __launch_bounds__(256) void pillar_stats_kernel(
    const float* __restrict__ pillars, const float* __restrict__ W,
    const float* __restrict__ gamma,
    const int* __restrict__ cx, const int* __restrict__ cy,
    const int* __restrict__ cb, const int* __restrict__ npoints,
    float* __restrict__ vsel, int* __restrict__ map,
    double* __restrict__ dsum, double* __restrict__ dsq, int P)
{
    __shared__ float4 pts[4][NPTS];      // 2 KB: 4 pillars x 32 points
    __shared__ float pinfo[4][6];        // mx, my, mz, npf, cxo, cyo per pillar
    __shared__ float ssum[4][NC], ssq[4][NC];

    const int tid = threadIdx.x;
    const int p0 = blockIdx.x * 4;

    // Phase A: stage points (coalesced float4) + per-pillar xyz sum over ALL 32 points
    // (reference centroid sums padding rows too) + pillar scalars.
    if (tid < 128) {
        int pl = tid >> 5, n = tid & 31;
        int p = p0 + pl;
        float4 v = make_float4(0.f, 0.f, 0.f, 0.f);
        if (p < P) v = ((const float4*)pillars)[(size_t)p * NPTS + n];
        pts[pl][n] = v;
        float sx = v.x, sy = v.y, sz = v.z;
        #pragma unroll
        for (int m = 16; m >= 1; m >>= 1) {
            sx += __shfl_xor(sx, m, 32);
            sy += __shfl_xor(sy, m, 32);
            sz += __shfl_xor(sz, m, 32);
        }
        if (n == 0 && p < P) {
            float npf = (float)npoints[p];
            pinfo[pl][0] = sx / npf;
            pinfo[pl][1] = sy / npf;
            pinfo[pl][2] = sz / npf;
            pinfo[pl][3] = npf;
            pinfo[pl][4] = cx[p] * VXc + X_OFFSET;
            pinfo[pl][5] = cy[p] * VYc + Y_OFFSET;
        }
    }
    // inverse map: cell -> pillar index
    if (tid >= 128 && tid < 132) {
        int p = p0 + (tid - 128);
        if (p < P) {
            int b = cb[p];
            map[(size_t)b * CELLS + (size_t)cy[p] * GRID_X + cx[p]] = p;
        }
    }
    __syncthreads();

    // Phase B: wave per pillar, lane = channel
    const int pl = tid >> 6, c = tid & 63;
    const int p = p0 + pl;
    float ssu = 0.f, sq2 = 0.f;
    if (p < P) {
        const float* w = W + c * 10;
        float w0 = w[0], w1 = w[1], w2 = w[2], w3 = w[3], w4 = w[4];
        float w5 = w[5], w6 = w[6], w7 = w[7], w8 = w[8], w9 = w[9];
        float sg = (gamma[c] >= 0.0f) ? 1.0f : -1.0f;   // sigma_c
        float Aw = sg * (w0 + w4 + w7);
        float Bw = sg * (w1 + w5 + w8);
        float Cw = sg * (w2 + w6);
        float Dw = sg * w3;
        float cxo = pinfo[pl][4];
        float cyo = pinfo[pl][5];
        float mx = pinfo[pl][0], my = pinfo[pl][1], mz = pinfo[pl][2];
        int np = (int)pinfo[pl][3];
        float E = sg * (-cxo * (w0 + w7) - cyo * (w1 + w8)
                        - mx * w4 - my * w5 - mz * w6 + Z_CONST * w9);
        float smax = -1e30f;
        #pragma unroll
        for (int n = 0; n < NPTS; ++n) {
            float4 pt = pts[pl][n];           // wave-uniform addr -> LDS broadcast
            float v = E;
            v = fmaf(pt.x, Aw, v);
            v = fmaf(pt.y, Bw, v);
            v = fmaf(pt.z, Cw, v);
            v = fmaf(pt.w, Dw, v);
            v = (n < np) ? v : 0.0f;          // masked points -> exactly 0 (matches ref)
            smax = fmaxf(smax, v);            // single extreme (sigma-space max)
            ssu += v;
            sq2 = fmaf(v, v, sq2);
        }
        vsel[(size_t)p * NC + c] = smax;
    }
    ssum[pl][c] = ssu;
    ssq[pl][c]  = sq2;
    __syncthreads();
    if (tid < NC) {
        float s = ssum[0][tid] + ssum[1][tid] + ssum[2][tid] + ssum[3][tid];
        float q = ssq[0][tid]  + ssq[1][tid]  + ssq[2][tid]  + ssq[3][tid];
        int slot = blockIdx.x & (NSLOTS - 1);
        atomicAdd(&dsum[slot * NC + tid], (double)s);
        atomicAdd(&dsq[slot * NC + tid],  (double)q);
    }
}

// Kernel B: fold slot accumulators -> sigma-space BN scale/shift per channel
__global__ void bn_params_kernel(const double* __restrict__ dsum,
                                 const double* __restrict__ dsq,
                                 const float* __restrict__ gamma,
                                 const float* __restrict__ beta,
                                 float* __restrict__ st, int P)
{
    int c = threadIdx.x;
    if (c < NC) {
        double s = 0.0, q = 0.0;
        for (int i = 0; i < NSLOTS; ++i) { s += dsum[i * NC + c]; q += dsq[i * NC + c]; }
        double cnt = (double)P * NPTS;
        double mu = s / cnt;                  // sigma-space mean
        double var = q / cnt - mu * mu;       // variance is sign-invariant
        float scale = fabsf(gamma[c]) * (float)(1.0 / sqrt(var + (double)BN_EPS));
        float shift = beta[c] - (float)mu * scale;
        st[c] = scale;          // always >= 0
        st[NC + c] = shift;
    }
}

// Kernel C: gather-style dense output, channel-outer, 4 cells/thread.
// int4 map loads, float4 stores (1 KB/wave burst per plane), st[] staged in LDS.
__global__ __launch_bounds__(256) void scatter_out_kernel(
    const int* __restrict__ map, const float* __restrict__ vsel,
    const float* __restrict__ st, float* __restrict__ out)
{
    __shared__ float ssc[NC], ssh[NC];
    if (threadIdx.x < NC) {
        ssc[threadIdx.x] = st[threadIdx.x];
        ssh[threadIdx.x] = st[NC + threadIdx.x];
    }
    __syncthreads();
    const int q4 = blockIdx.x * 256 + threadIdx.x;  // quad of cells within batch
    const int b = blockIdx.y;
    if (q4 >= QUADS) return;
    const int4 m4 = ((const int4*)(map + (size_t)b * CELLS))[q4];
    const bool bx = m4.x >= 0, by = m4.y >= 0, bz = m4.z >= 0, bw = m4.w >= 0;
    // clamped row pointers: empty lanes all hit vsel row 0 (one L1-resident line)
    const float* vpx = vsel + (size_t)(bx ? m4.x : 0) * NC;
    const float* vpy = vsel + (size_t)(by ? m4.y : 0) * NC;
    const float* vpz = vsel + (size_t)(bz ? m4.z : 0) * NC;
    const float* vpw = vsel + (size_t)(bw ? m4.w : 0) * NC;
    float* ob = out + (size_t)b * NC * CELLS + (size_t)q4 * 4;
    #pragma unroll 8
    for (int c = 0; c < NC; ++c) {
        float sc = ssc[c], sh = ssh[c];       // wave-uniform LDS broadcast
        float4 r;
        r.x = bx ? fmaxf(fmaf(sc, vpx[c], sh), 0.0f) : 0.0f;
        r.y = by ? fmaxf(fmaf(sc, vpy[c], sh), 0.0f) : 0.0f;
        r.z = bz ? fmaxf(fmaf(sc, vpz[c], sh), 0.0f) : 0.0f;
        r.w = bw ? fmaxf(fmaf(sc, vpw[c], sh), 0.0f) : 0.0f;
        *(float4*)(ob + (size_t)c * CELLS) = r;
    }
}

extern "C" void kernel_launch(void* const* d_in, const int* in_sizes, int n_in,
                              void* d_out, int out_size, void* d_ws, size_t ws_size,
                              hipStream_t stream) {
    const float* pillars = (const float*)d_in[0];
    const float* W       = (const float*)d_in[1];
    const float* gamma   = (const float*)d_in[2];
    const float* beta    = (const float*)d_in[3];
    const int*   cx      = (const int*)d_in[4];
    const int*   cy      = (const int*)d_in[5];
    const int*   cb      = (const int*)d_in[6];
    const int*   np      = (const int*)d_in[7];
    const int P = in_sizes[4];      // 48000

    // workspace carve-up (~16 MB)
    char* ws = (char*)d_ws;
    float* vsel = (float*)ws;                         // P*NC floats (sigma-space extreme)
    int*   map  = (int*)(vsel + (size_t)P * NC);
    size_t mapN = (size_t)NB * CELLS;
    double* dsum = (double*)(((uintptr_t)(map + mapN) + 255) & ~(uintptr_t)255);
    double* dsq  = dsum + NSLOTS * NC;
    float*  st   = (float*)(dsq + NSLOTS * NC);

    hipMemsetAsync(map, 0xFF, mapN * sizeof(int), stream);                 // -1 = empty
    hipMemsetAsync(dsum, 0, (size_t)NSLOTS * NC * 2 * sizeof(double), stream);

    pillar_stats_kernel<<<(P + 3) / 4, 256, 0, stream>>>(
        pillars, W, gamma, cx, cy, cb, np, vsel, map, dsum, dsq, P);
    bn_params_kernel<<<1, 64, 0, stream>>>(dsum, dsq, gamma, beta, st, P);
    scatter_out_kernel<<<dim3((QUADS + 255) / 256, NB), 256, 0, stream>>>(
        map, vsel, st, (float*)d_out);
}